// Round 1
// 1210.917 us; speedup vs baseline: 1.0357x; 1.0357x over previous
//
#include <hip/hip_runtime.h>
#include <math.h>

#define N_NODES 100000
#define N_EDGES 150000
#define D 512
#define H 8
#define NEG_SLOPE 0.2f
#define NBR 782          // row blocks of 128 over 100000 rows
#define NBLK (NBR * 4)   // 3128 blocks per GEMM half

typedef __attribute__((ext_vector_type(8))) short bf16x8;
typedef __attribute__((ext_vector_type(4))) float f32x4;

// ---------- helpers ----------
__device__ __forceinline__ float bf2f(unsigned short u) { return __uint_as_float(((unsigned int)u) << 16); }
__device__ __forceinline__ unsigned short f2bf(float f) {
    unsigned int u = __float_as_uint(f);
    unsigned int r = u + 0x7FFFu + ((u >> 16) & 1u);
    return (unsigned short)(r >> 16);
}
__device__ __forceinline__ unsigned int pkbf(float a, float b) {
    unsigned int ua = __float_as_uint(a) + 0x8000u;
    unsigned int ub = __float_as_uint(b) + 0x8000u;
    return (ua >> 16) | (ub & 0xFFFF0000u);
}
__device__ __forceinline__ void gl_lds16(const void* g, void* l) {
    __builtin_amdgcn_global_load_lds((const __attribute__((address_space(1))) void*)g,
                                     (__attribute__((address_space(3))) void*)l, 16, 0, 0);
}
// fast tanh: 1 - 2/(e^{2x}+1); exp via hw exp2 path, rcp via v_rcp_f32 (~1ulp).
// |err| ~1e-6, averaged over 100k rows downstream -> negligible.
__device__ __forceinline__ float fast_tanh(float x) {
    float e = __expf(2.0f * x);
    float r;
    asm("v_rcp_f32 %0, %1" : "=v"(r) : "v"(e + 1.0f));
    return 1.0f - 2.0f * r;
}
// XCD-aware swizzle: groups of 32 linear ids = 8 row-blocks x 4 col-blocks;
// id%8 (the XCD on round-robin dispatch) is the row-block within the group, so
// the 4 col tiles of one row-block share an XCD -> A rows fetched once from HBM.
__device__ __forceinline__ void map_block(int lin, int& rblk, int& cblk) {
    int g = lin >> 5;
    if (g < (NBR >> 3)) { rblk = g * 8 + (lin & 7); cblk = (lin >> 3) & 3; }
    else { int idx = lin - (NBR >> 3) * 32; rblk = (NBR & ~7) + (idx >> 2); cblk = idx & 3; }
}

// ---------- CSR build ----------
__global__ __launch_bounds__(256)
void hist_edges(const int* __restrict__ e2o, const int* __restrict__ o2o, int* __restrict__ deg) {
    int i = blockIdx.x * 256 + threadIdx.x;
    if (i < N_EDGES) atomicAdd(&deg[e2o[N_EDGES + i]], 1);
    else if (i < 2 * N_EDGES) atomicAdd(&deg[N_NODES + o2o[N_EDGES + (i - N_EDGES)]], 1);
}

__global__ __launch_bounds__(256)
void scan1(const int* __restrict__ deg, int* __restrict__ rowptr, int* __restrict__ partials, int n) {
    __shared__ int lds[256];
    int t = threadIdx.x, b = blockIdx.x;
    int base = b * 1024 + t * 4;
    int d0 = (base + 0 < n) ? deg[base + 0] : 0;
    int d1 = (base + 1 < n) ? deg[base + 1] : 0;
    int d2 = (base + 2 < n) ? deg[base + 2] : 0;
    int d3 = (base + 3 < n) ? deg[base + 3] : 0;
    int s = d0 + d1 + d2 + d3;
    lds[t] = s;
    __syncthreads();
    for (int off = 1; off < 256; off <<= 1) {
        int v = (t >= off) ? lds[t - off] : 0;
        __syncthreads();
        lds[t] += v;
        __syncthreads();
    }
    int incl = lds[t];
    int eb = incl - s;
    if (base + 0 < n) rowptr[base + 0] = eb;
    if (base + 1 < n) rowptr[base + 1] = eb + d0;
    if (base + 2 < n) rowptr[base + 2] = eb + d0 + d1;
    if (base + 3 < n) rowptr[base + 3] = eb + d0 + d1 + d2;
    if (t == 255) partials[b] = incl;
}

// merged scan2+scan3: every block redundantly scans the (<=256) partials in LDS
__global__ __launch_bounds__(256)
void scan23(int* __restrict__ rowptr, const int* __restrict__ partials,
            int* __restrict__ cursor, int n, int total, int nb) {
    __shared__ int lds[256];
    int t = threadIdx.x, b = blockIdx.x;
    lds[t] = (t < nb) ? partials[t] : 0;
    __syncthreads();
    for (int off = 1; off < 256; off <<= 1) {
        int v = (t >= off) ? lds[t - off] : 0;
        __syncthreads();
        lds[t] += v;
        __syncthreads();
    }
    int add = (b == 0) ? 0 : lds[b - 1];
    int base = b * 1024 + t * 4;
    #pragma unroll
    for (int j = 0; j < 4; ++j) {
        if (base + j < n) {
            int v = rowptr[base + j] + add;
            rowptr[base + j] = v;
            cursor[base + j] = v;
        }
    }
    if (b == 0 && t == 0) rowptr[n] = total;
}

__global__ __launch_bounds__(256)
void fill_csr(const int* __restrict__ e2o, const int* __restrict__ o2o,
              int* __restrict__ cursor, int* __restrict__ csr) {
    int i = blockIdx.x * 256 + threadIdx.x;
    if (i < N_EDGES) {
        int d = e2o[N_EDGES + i];
        int p = atomicAdd(&cursor[d], 1);
        csr[p] = e2o[i];
    } else if (i < 2 * N_EDGES) {
        int j = i - N_EDGES;
        int d = o2o[N_EDGES + j];
        int p = atomicAdd(&cursor[N_NODES + d], 1);
        csr[p] = o2o[j];
    }
}

// ---------- three W[512,512] fp32 -> Wt[n][k] bf16 in one dispatch ----------
__global__ __launch_bounds__(256)
void transpose3(const float* __restrict__ W0, const float* __restrict__ W1, const float* __restrict__ W2,
                unsigned short* __restrict__ T0, unsigned short* __restrict__ T1, unsigned short* __restrict__ T2) {
    __shared__ float tile[32][33];
    int z = blockIdx.z;
    const float* W = (z == 0) ? W0 : (z == 1) ? W1 : W2;
    unsigned short* T = (z == 0) ? T0 : (z == 1) ? T1 : T2;
    int bx = blockIdx.x, by = blockIdx.y;
    int t = threadIdx.x, tx = t & 31, ty = t >> 5;
    #pragma unroll
    for (int p = 0; p < 4; ++p) {
        int k = by * 32 + ty + p * 8;
        tile[ty + p * 8][tx] = W[(size_t)k * D + bx * 32 + tx];
    }
    __syncthreads();
    #pragma unroll
    for (int p = 0; p < 4; ++p) {
        int n = bx * 32 + ty + p * 8;
        T[(size_t)n * D + by * 32 + tx] = f2bf(tile[tx][ty + p * 8]);
    }
}

// ---------- x_o, x_e fp32 -> bf16 in one dispatch ----------
__global__ __launch_bounds__(256)
void convert2(const float4* __restrict__ x0, const float4* __restrict__ x1,
              uint2* __restrict__ y0, uint2* __restrict__ y1) {
    const int n4 = N_NODES * D / 4;
    int i = blockIdx.x * 256 + threadIdx.x;
    const float4* s; uint2* d; int j;
    if (i < n4) { s = x0; d = y0; j = i; }
    else { s = x1; d = y1; j = i - n4; }
    float4 v = s[j];
    uint2 o; o.x = pkbf(v.x, v.y); o.y = pkbf(v.z, v.w);
    d[j] = o;
}

// ---------- merged projection GEMMs + fused per-head attention dots ----------
// K-loop: double-buffered LDS, prefetch tile k+1 before computing tile k,
// ONE __syncthreads() per iter at the END (its vmcnt(0) drain lands after
// ~300cy of ds_read+MFMA -> load latency mostly hidden; also guarantees all
// waves finished reading buf before next iter's stage overwrites it).
__global__ __launch_bounds__(256)
void gemm_proj2(const unsigned short* __restrict__ A0, const unsigned short* __restrict__ A1,
                const unsigned short* __restrict__ Bt0, const unsigned short* __restrict__ Bt1,
                const float* __restrict__ b0, const float* __restrict__ b1,
                unsigned short* __restrict__ C0, unsigned short* __restrict__ C1,
                const float* __restrict__ at00, const float* __restrict__ at01, const float* __restrict__ at02,
                float* __restrict__ ao00, float* __restrict__ ao01, float* __restrict__ ao02,
                const float* __restrict__ at10, float* __restrict__ ao10)
{
    __shared__ __align__(16) unsigned short As[2][4096];   // [buf][8 subtiles of [16 rows][32 k]]
    __shared__ __align__(16) unsigned short Bs[2][4096];
    const int M = N_NODES;
    int lin = blockIdx.x;
    int half = (lin >= NBLK) ? 1 : 0;
    lin -= half * NBLK;
    int rblk, cblk; map_block(lin, rblk, cblk);
    const unsigned short* A  = half ? A1 : A0;
    const unsigned short* Bt = half ? Bt1 : Bt0;
    const float* bias        = half ? b1 : b0;
    unsigned short* C        = half ? C1 : C0;
    const int natt = half ? 1 : 3;
    const float* attA = half ? at10 : at00;
    const float* attB = at01;
    const float* attC = at02;
    float* aoA = half ? ao10 : ao00;
    float* aoB = ao01;
    float* aoC = ao02;

    const int tid = threadIdx.x, lane = tid & 63, wave = tid >> 6;
    const int rb = rblk * 128, cb = cblk * 128;
    const int wm = (wave >> 1) * 64, wn = (wave & 1) * 64;

    // staging: each wave fills subtiles {2w, 2w+1} of A and B.
    // lane l -> row (l&15) of subtile, k-chunk (l>>4)*8 elems; LDS dest = base + l*16B
    const unsigned short* agp[2]; const unsigned short* bgp[2];
    #pragma unroll
    for (int c = 0; c < 2; ++c) {
        int s = wave * 2 + c;
        int rA = rb + s * 16 + (lane & 15); if (rA > M - 1) rA = M - 1;
        agp[c] = A + (size_t)rA * D + (lane >> 4) * 8;
        int rB = cb + s * 16 + (lane & 15);
        bgp[c] = Bt + (size_t)rB * D + (lane >> 4) * 8;
    }

    f32x4 acc[4][4];
    #pragma unroll
    for (int i = 0; i < 4; ++i)
        #pragma unroll
        for (int j = 0; j < 4; ++j) acc[i][j] = (f32x4){0.f, 0.f, 0.f, 0.f};

    // prologue: stage tile 0 into buffer 0
    #pragma unroll
    for (int c = 0; c < 2; ++c) {
        int s = wave * 2 + c;
        gl_lds16(agp[c], &As[0][s * 512]); agp[c] += 32;
        gl_lds16(bgp[c], &Bs[0][s * 512]); bgp[c] += 32;
    }
    __syncthreads();

    int buf = 0;
    for (int k = 0; k < 16; ++k) {
        if (k < 15) {
            #pragma unroll
            for (int c = 0; c < 2; ++c) {
                int s = wave * 2 + c;
                gl_lds16(agp[c], &As[buf ^ 1][s * 512]); agp[c] += 32;
                gl_lds16(bgp[c], &Bs[buf ^ 1][s * 512]); bgp[c] += 32;
            }
        }
        bf16x8 af[4], bfr[4];
        #pragma unroll
        for (int mi = 0; mi < 4; ++mi) af[mi] = *(const bf16x8*)&As[buf][((wave >> 1) * 4 + mi) * 512 + lane * 8];
        #pragma unroll
        for (int ni = 0; ni < 4; ++ni) bfr[ni] = *(const bf16x8*)&Bs[buf][((wave & 1) * 4 + ni) * 512 + lane * 8];
        #pragma unroll
        for (int mi = 0; mi < 4; ++mi)
            #pragma unroll
            for (int ni = 0; ni < 4; ++ni)
                acc[mi][ni] = __builtin_amdgcn_mfma_f32_16x16x32_bf16(af[mi], bfr[ni], acc[mi][ni], 0, 0, 0);
        __syncthreads();
        buf ^= 1;
    }

    // epilogue: bias + bf16 store + per-head attention dots (this wave's 64 cols = one head)
    float bb[4], av0[4], av1[4], av2[4];
    const int head = (cb + wn) >> 6;
    #pragma unroll
    for (int ni = 0; ni < 4; ++ni) {
        int ci = ni * 16 + (lane & 15);
        bb[ni] = bias[cb + wn + ci];
        av0[ni] = attA[head * 64 + ci];
        if (natt > 1) { av1[ni] = attB[head * 64 + ci]; av2[ni] = attC[head * 64 + ci]; }
    }
    #pragma unroll
    for (int mi = 0; mi < 4; ++mi) {
        #pragma unroll
        for (int r = 0; r < 4; ++r) {
            int rg = rb + wm + mi * 16 + (lane >> 4) * 4 + r;
            bool ok = rg < M;
            float v[4];
            #pragma unroll
            for (int ni = 0; ni < 4; ++ni) v[ni] = acc[mi][ni][r] + bb[ni];
            if (ok) {
                size_t base = (size_t)rg * D + cb + wn + (lane & 15);
                #pragma unroll
                for (int ni = 0; ni < 4; ++ni) C[base + ni * 16] = f2bf(v[ni]);
            }
            float s0 = v[0] * av0[0] + v[1] * av0[1] + v[2] * av0[2] + v[3] * av0[3];
            float s1 = 0.f, s2 = 0.f;
            if (natt > 1) {
                s1 = v[0] * av1[0] + v[1] * av1[1] + v[2] * av1[2] + v[3] * av1[3];
                s2 = v[0] * av2[0] + v[1] * av2[1] + v[2] * av2[2] + v[3] * av2[3];
            }
            #pragma unroll
            for (int m2 = 1; m2 < 16; m2 <<= 1) {
                s0 += __shfl_xor(s0, m2);
                if (natt > 1) { s1 += __shfl_xor(s1, m2); s2 += __shfl_xor(s2, m2); }
            }
            if (ok && (lane & 15) == 0) {
                aoA[rg * H + head] = s0;
                if (natt > 1) { aoB[rg * H + head] = s1; aoC[rg * H + head] = s2; }
            }
        }
    }
}

// ---------- merged CSR aggregation (both metapaths): one wave per dst node ----------
__global__ __launch_bounds__(256)
void aggregate2(const int* __restrict__ rowptr, const int* __restrict__ csr,
                const float* __restrict__ aS0, const float* __restrict__ aD0, const unsigned short* __restrict__ hE,
                const float* __restrict__ aS1, const float* __restrict__ aD1, const unsigned short* __restrict__ hO,
                unsigned short* __restrict__ out0, unsigned short* __restrict__ out1)
{
    int gw = (blockIdx.x * 256 + threadIdx.x) >> 6;
    int lane = threadIdx.x & 63;
    if (gw >= 2 * N_NODES) return;
    int half = gw >= N_NODES;
    int node = gw - half * N_NODES;
    const float* a_src = half ? aS1 : aS0;
    const float* a_dst = half ? aD1 : aD0;
    const unsigned short* h = half ? hO : hE;
    unsigned short* out = half ? out1 : out0;

    int beg = rowptr[gw], end = rowptr[gw + 1];
    int hh = lane & 7;
    float adst = a_dst[node * H + hh];

    float amax = -1e30f;
    for (int p = beg; p < end; ++p) {
        int s = csr[p];
        float al = a_src[s * H + hh] + adst;
        al = (al >= 0.f) ? al : NEG_SLOPE * al;
        amax = fmaxf(amax, al);
    }
    float denom = 0.f;
    for (int p = beg; p < end; ++p) {
        int s = csr[p];
        float al = a_src[s * H + hh] + adst;
        al = (al >= 0.f) ? al : NEG_SLOPE * al;
        denom += expf(al - amax);
    }
    float inv = 1.f / (denom + 1e-16f);

    float acc[8] = {0.f, 0.f, 0.f, 0.f, 0.f, 0.f, 0.f, 0.f};
    for (int p = beg; p < end; ++p) {
        int s = csr[p];
        float al = a_src[s * H + hh] + adst;
        al = (al >= 0.f) ? al : NEG_SLOPE * al;
        float w = expf(al - amax) * inv;
        const unsigned short* hp = h + (size_t)s * D;
        #pragma unroll
        for (int h2 = 0; h2 < 8; ++h2) {
            float wh = __shfl(w, h2);
            acc[h2] += bf2f(hp[h2 * 64 + lane]) * wh;
        }
    }
    size_t base = (size_t)node * D;
    #pragma unroll
    for (int h2 = 0; h2 < 8; ++h2)
        out[base + h2 * 64 + lane] = f2bf(fmaxf(acc[h2], 0.f));
}

// ---------- merged column sums of both relu'd bf16 matrices ----------
__global__ __launch_bounds__(256)
void colsum2(const unsigned short* __restrict__ ob0, const unsigned short* __restrict__ ob1,
             float* __restrict__ colsum)
{
    __shared__ float red[512];
    int b = blockIdx.x;
    int half = b >= NBR;
    const unsigned short* ob = half ? ob1 : ob0;
    float* cs = colsum + half * 512;
    int t = threadIdx.x;
    int r0 = (b - half * NBR) * 128;
    int c8 = t & 63;
    float s[8] = {0.f, 0.f, 0.f, 0.f, 0.f, 0.f, 0.f, 0.f};
    for (int it = 0; it < 32; ++it) {
        int row = r0 + it * 4 + (t >> 6);
        if (row < N_NODES) {
            uint4 v = *((const uint4*)(ob + (size_t)row * D) + c8);
            s[0] += bf2f((unsigned short)(v.x & 0xFFFF)); s[1] += bf2f((unsigned short)(v.x >> 16));
            s[2] += bf2f((unsigned short)(v.y & 0xFFFF)); s[3] += bf2f((unsigned short)(v.y >> 16));
            s[4] += bf2f((unsigned short)(v.z & 0xFFFF)); s[5] += bf2f((unsigned short)(v.z >> 16));
            s[6] += bf2f((unsigned short)(v.w & 0xFFFF)); s[7] += bf2f((unsigned short)(v.w >> 16));
        }
    }
    red[t] = 0.f; red[t + 256] = 0.f;
    __syncthreads();
    #pragma unroll
    for (int j = 0; j < 8; ++j) atomicAdd(&red[c8 * 8 + j], s[j]);
    __syncthreads();
    atomicAdd(&cs[t & 511], red[t]);
    atomicAdd(&cs[(t + 256) & 511], red[t + 256]);
}

// ---------- merged semantic-K GEMMs: ksum[half][f] += sum_rows tanh((A@Wkl^T + b)[row,f]) ----------
__global__ __launch_bounds__(256)
void gemm_tanh2(const unsigned short* __restrict__ Ah0, const unsigned short* __restrict__ Ah1,
                const unsigned short* __restrict__ Bt, const float* __restrict__ bias,
                float* __restrict__ ksum)
{
    __shared__ __align__(16) unsigned short As[2][4096];
    __shared__ __align__(16) unsigned short Bs[2][4096];
    const int M = N_NODES;
    int lin = blockIdx.x;
    int half = (lin >= NBLK) ? 1 : 0;
    lin -= half * NBLK;
    int rblk, cblk; map_block(lin, rblk, cblk);
    const unsigned short* A = half ? Ah1 : Ah0;
    float* ks = ksum + half * 512;

    const int tid = threadIdx.x, lane = tid & 63, wave = tid >> 6;
    const int rb = rblk * 128, cb = cblk * 128;
    const int wm = (wave >> 1) * 64, wn = (wave & 1) * 64;

    const unsigned short* agp[2]; const unsigned short* bgp[2];
    #pragma unroll
    for (int c = 0; c < 2; ++c) {
        int s = wave * 2 + c;
        int rA = rb + s * 16 + (lane & 15); if (rA > M - 1) rA = M - 1;
        agp[c] = A + (size_t)rA * D + (lane >> 4) * 8;
        int rB = cb + s * 16 + (lane & 15);
        bgp[c] = Bt + (size_t)rB * D + (lane >> 4) * 8;
    }

    f32x4 acc[4][4];
    #pragma unroll
    for (int i = 0; i < 4; ++i)
        #pragma unroll
        for (int j = 0; j < 4; ++j) acc[i][j] = (f32x4){0.f, 0.f, 0.f, 0.f};

    // prologue: stage tile 0 into buffer 0
    #pragma unroll
    for (int c = 0; c < 2; ++c) {
        int s = wave * 2 + c;
        gl_lds16(agp[c], &As[0][s * 512]); agp[c] += 32;
        gl_lds16(bgp[c], &Bs[0][s * 512]); bgp[c] += 32;
    }
    __syncthreads();

    int buf = 0;
    for (int k = 0; k < 16; ++k) {
        if (k < 15) {
            #pragma unroll
            for (int c = 0; c < 2; ++c) {
                int s = wave * 2 + c;
                gl_lds16(agp[c], &As[buf ^ 1][s * 512]); agp[c] += 32;
                gl_lds16(bgp[c], &Bs[buf ^ 1][s * 512]); bgp[c] += 32;
            }
        }
        bf16x8 af[4], bfr[4];
        #pragma unroll
        for (int mi = 0; mi < 4; ++mi) af[mi] = *(const bf16x8*)&As[buf][((wave >> 1) * 4 + mi) * 512 + lane * 8];
        #pragma unroll
        for (int ni = 0; ni < 4; ++ni) bfr[ni] = *(const bf16x8*)&Bs[buf][((wave & 1) * 4 + ni) * 512 + lane * 8];
        #pragma unroll
        for (int mi = 0; mi < 4; ++mi)
            #pragma unroll
            for (int ni = 0; ni < 4; ++ni)
                acc[mi][ni] = __builtin_amdgcn_mfma_f32_16x16x32_bf16(af[mi], bfr[ni], acc[mi][ni], 0, 0, 0);
        __syncthreads();
        buf ^= 1;
    }

    float bb[4];
    #pragma unroll
    for (int ni = 0; ni < 4; ++ni) bb[ni] = bias[cb + wn + ni * 16 + (lane & 15)];
    float cs[4] = {0.f, 0.f, 0.f, 0.f};
    #pragma unroll
    for (int mi = 0; mi < 4; ++mi) {
        #pragma unroll
        for (int r = 0; r < 4; ++r) {
            int rg = rb + wm + mi * 16 + (lane >> 4) * 4 + r;
            if (rg < M) {
                #pragma unroll
                for (int ni = 0; ni < 4; ++ni)
                    cs[ni] += fast_tanh(acc[mi][ni][r] + bb[ni]);
            }
        }
    }
    __syncthreads();
    float* red = (float*)As;
    if (tid < 128) red[tid] = 0.f;
    __syncthreads();
    #pragma unroll
    for (int ni = 0; ni < 4; ++ni) atomicAdd(&red[wn + ni * 16 + (lane & 15)], cs[ni]);
    __syncthreads();
    if (tid < 128) atomicAdd(&ks[cb + tid], red[tid]);
}

// ---------- final semantic softmax + pool + linear ----------
__global__ __launch_bounds__(256)
void finalize(const float* __restrict__ ksum, const float* __restrict__ colsum,
              const float* __restrict__ q_sem, const float* __restrict__ lin_w,
              const float* __restrict__ lin_b, float* __restrict__ dout)
{
    __shared__ float red[256];
    __shared__ float semsh[2];
    int t = threadIdx.x;
    const float invN = 1.0f / (float)N_NODES;
    float p0 = ksum[t] * q_sem[t] + ksum[t + 256] * q_sem[t + 256];
    float p1 = ksum[512 + t] * q_sem[t] + ksum[512 + t + 256] * q_sem[t + 256];

    red[t] = p0; __syncthreads();
    for (int s = 128; s > 0; s >>= 1) { if (t < s) red[t] += red[t + s]; __syncthreads(); }
    float S0 = red[0]; __syncthreads();
    red[t] = p1; __syncthreads();
    for (int s = 128; s > 0; s >>= 1) { if (t < s) red[t] += red[t + s]; __syncthreads(); }
    float S1 = red[0]; __syncthreads();

    if (t == 0) {
        float a0 = S0 * invN, a1 = S1 * invN;
        float mx = fmaxf(a0, a1);
        float e0 = expf(a0 - mx), e1 = expf(a1 - mx);
        semsh[0] = e0 / (e0 + e1);
        semsh[1] = e1 / (e0 + e1);
    }
    __syncthreads();
    float sem0 = semsh[0], sem1 = semsh[1];

    float o0 = 0.f, o1 = 0.f;
    #pragma unroll
    for (int q = 0; q < 2; ++q) {
        int f = t + q * 256;
        float pooled = (sem0 * colsum[f] + sem1 * colsum[512 + f]) * invN;
        o0 += pooled * lin_w[f * 2 + 0];
        o1 += pooled * lin_w[f * 2 + 1];
    }
    red[t] = o0; __syncthreads();
    for (int s = 128; s > 0; s >>= 1) { if (t < s) red[t] += red[t + s]; __syncthreads(); }
    if (t == 0) dout[0] = red[0] + lin_b[0];
    __syncthreads();
    red[t] = o1; __syncthreads();
    for (int s = 128; s > 0; s >>= 1) { if (t < s) red[t] += red[t + s]; __syncthreads(); }
    if (t == 0) dout[1] = red[0] + lin_b[1];
}

extern "C" void kernel_launch(void* const* d_in, const int* in_sizes, int n_in,
                              void* d_out, int out_size, void* d_ws, size_t ws_size,
                              hipStream_t stream)
{
    const float* x_o    = (const float*)d_in[0];
    const float* x_e    = (const float*)d_in[1];
    const int*   e2o    = (const int*)d_in[2];
    const int*   o2o    = (const int*)d_in[3];
    const float* pow_   = (const float*)d_in[4];
    const float* pob    = (const float*)d_in[5];
    const float* pew    = (const float*)d_in[6];
    const float* peb    = (const float*)d_in[7];
    const float* as_e2o = (const float*)d_in[8];
    const float* ad_e2o = (const float*)d_in[9];
    const float* as_o2o = (const float*)d_in[10];
    const float* ad_o2o = (const float*)d_in[11];
    const float* klw    = (const float*)d_in[12];
    const float* klb    = (const float*)d_in[13];
    const float* qsem   = (const float*)d_in[14];
    const float* linw   = (const float*)d_in[15];
    const float* linb   = (const float*)d_in[16];

    char* ws = (char*)d_ws;
    size_t off = 0;
    auto alloc = [&](size_t bytes) { void* p = ws + off; off += (bytes + 255) & ~(size_t)255; return p; };

    unsigned short* xbf_o = (unsigned short*)alloc((size_t)N_NODES * D * 2);
    unsigned short* xbf_e = (unsigned short*)alloc((size_t)N_NODES * D * 2);
    unsigned short* h_o   = (unsigned short*)alloc((size_t)N_NODES * D * 2);
    unsigned short* h_e   = (unsigned short*)alloc((size_t)N_NODES * D * 2);
    unsigned short* obf0  = (unsigned short*)alloc((size_t)N_NODES * D * 2);
    unsigned short* obf1  = (unsigned short*)alloc((size_t)N_NODES * D * 2);
    unsigned short* wt_po = (unsigned short*)alloc((size_t)D * D * 2);
    unsigned short* wt_pe = (unsigned short*)alloc((size_t)D * D * 2);
    unsigned short* wt_kl = (unsigned short*)alloc((size_t)D * D * 2);
    float* aS0 = (float*)alloc((size_t)N_NODES * H * 4);
    float* aD0 = (float*)alloc((size_t)N_NODES * H * 4);
    float* aS1 = (float*)alloc((size_t)N_NODES * H * 4);
    float* aD1 = (float*)alloc((size_t)N_NODES * H * 4);
    // contiguous zeroed region: colsum[1024] | ksum[1024] | deg[2N]
    int* misc    = (int*)alloc((2048 + 2 * N_NODES) * 4);
    float* colsum = (float*)misc;
    float* ksum   = colsum + 1024;
    int* deg      = misc + 2048;
    int* cursor  = (int*)alloc(2 * N_NODES * 4);
    int* rowptr  = (int*)alloc((2 * N_NODES + 1) * 4);
    int* partials= (int*)alloc(256 * 4);
    int* csr     = (int*)alloc(2 * N_EDGES * 4);

    const int NSC = 2 * N_NODES;
    const int NB1 = (NSC + 1023) / 1024;              // 196
    const int EH  = (2 * N_EDGES + 255) / 256;        // 1172

    hipMemsetAsync(misc, 0, (size_t)(2048 + 2 * N_NODES) * 4, stream);

    // CSR build
    hist_edges<<<EH, 256, 0, stream>>>(e2o, o2o, deg);
    scan1<<<NB1, 256, 0, stream>>>(deg, rowptr, partials, NSC);
    scan23<<<NB1, 256, 0, stream>>>(rowptr, partials, cursor, NSC, 2 * N_EDGES, NB1);
    fill_csr<<<EH, 256, 0, stream>>>(e2o, o2o, cursor, csr);

    // weights -> bf16 W^T (one dispatch), inputs -> bf16 (one dispatch)
    transpose3<<<dim3(16, 16, 3), 256, 0, stream>>>(pow_, pew, klw, wt_po, wt_pe, wt_kl);
    convert2<<<(2 * N_NODES * D / 4) / 256, 256, 0, stream>>>(
        (const float4*)x_o, (const float4*)x_e, (uint2*)xbf_o, (uint2*)xbf_e);

    // merged projections + fused attention dots
    gemm_proj2<<<2 * NBLK, 256, 0, stream>>>(
        xbf_o, xbf_e, wt_po, wt_pe, pob, peb, h_o, h_e,
        ad_e2o, as_o2o, ad_o2o, aD0, aS1, aD1,
        as_e2o, aS0);

    // merged aggregation, column sums, semantic-K GEMMs
    aggregate2<<<(2 * N_NODES * 64) / 256, 256, 0, stream>>>(
        rowptr, csr, aS0, aD0, h_e, aS1, aD1, h_o, obf0, obf1);
    colsum2<<<2 * NBR, 256, 0, stream>>>(obf0, obf1, colsum);
    gemm_tanh2<<<2 * NBLK, 256, 0, stream>>>(obf0, obf1, wt_kl, klb, ksum);

    finalize<<<1, 256, 0, stream>>>(ksum, colsum, qsem, linw, linb, (float*)d_out);
}

// Round 3
// 1186.819 us; speedup vs baseline: 1.0568x; 1.0203x over previous
//
#include <hip/hip_runtime.h>
#include <math.h>

#define N_NODES 100000
#define N_EDGES 150000
#define D 512
#define H 8
#define NEG_SLOPE 0.2f
#define NBR 782          // row blocks of 128 over 100000 rows
#define NBLK (NBR * 4)   // 3128 blocks per GEMM half

typedef __attribute__((ext_vector_type(8))) short bf16x8;
typedef __attribute__((ext_vector_type(4))) float f32x4;

// ---------- helpers ----------
__device__ __forceinline__ float bf2f(unsigned short u) { return __uint_as_float(((unsigned int)u) << 16); }
__device__ __forceinline__ unsigned short f2bf(float f) {
    unsigned int u = __float_as_uint(f);
    unsigned int r = u + 0x7FFFu + ((u >> 16) & 1u);
    return (unsigned short)(r >> 16);
}
__device__ __forceinline__ unsigned int pkbf(float a, float b) {
    unsigned int ua = __float_as_uint(a) + 0x8000u;
    unsigned int ub = __float_as_uint(b) + 0x8000u;
    return (ua >> 16) | (ub & 0xFFFF0000u);
}
__device__ __forceinline__ void gl_lds16(const void* g, void* l) {
    __builtin_amdgcn_global_load_lds((const __attribute__((address_space(1))) void*)g,
                                     (__attribute__((address_space(3))) void*)l, 16, 0, 0);
}
// fast tanh: 1 - 2/(e^{2x}+1); exp via hw exp2 path, rcp via v_rcp_f32 (~1ulp).
__device__ __forceinline__ float fast_tanh(float x) {
    float e = __expf(2.0f * x);
    float r;
    asm("v_rcp_f32 %0, %1" : "=v"(r) : "v"(e + 1.0f));
    return 1.0f - 2.0f * r;
}
// XCD-aware swizzle: groups of 32 linear ids = 8 row-blocks x 4 col-blocks;
// id%8 (the XCD on round-robin dispatch) is the row-block within the group, so
// the 4 col tiles of one row-block share an XCD -> A rows fetched once from HBM.
__device__ __forceinline__ void map_block(int lin, int& rblk, int& cblk) {
    int g = lin >> 5;
    if (g < (NBR >> 3)) { rblk = g * 8 + (lin & 7); cblk = (lin >> 3) & 3; }
    else { int idx = lin - (NBR >> 3) * 32; rblk = (NBR & ~7) + (idx >> 2); cblk = idx & 3; }
}

// ---------- CSR build ----------
__global__ __launch_bounds__(256)
void hist_edges(const int* __restrict__ e2o, const int* __restrict__ o2o, int* __restrict__ deg) {
    int i = blockIdx.x * 256 + threadIdx.x;
    if (i < N_EDGES) atomicAdd(&deg[e2o[N_EDGES + i]], 1);
    else if (i < 2 * N_EDGES) atomicAdd(&deg[N_NODES + o2o[N_EDGES + (i - N_EDGES)]], 1);
}

__global__ __launch_bounds__(256)
void scan1(const int* __restrict__ deg, int* __restrict__ rowptr, int* __restrict__ partials, int n) {
    __shared__ int lds[256];
    int t = threadIdx.x, b = blockIdx.x;
    int base = b * 1024 + t * 4;
    int d0 = (base + 0 < n) ? deg[base + 0] : 0;
    int d1 = (base + 1 < n) ? deg[base + 1] : 0;
    int d2 = (base + 2 < n) ? deg[base + 2] : 0;
    int d3 = (base + 3 < n) ? deg[base + 3] : 0;
    int s = d0 + d1 + d2 + d3;
    lds[t] = s;
    __syncthreads();
    for (int off = 1; off < 256; off <<= 1) {
        int v = (t >= off) ? lds[t - off] : 0;
        __syncthreads();
        lds[t] += v;
        __syncthreads();
    }
    int incl = lds[t];
    int eb = incl - s;
    if (base + 0 < n) rowptr[base + 0] = eb;
    if (base + 1 < n) rowptr[base + 1] = eb + d0;
    if (base + 2 < n) rowptr[base + 2] = eb + d0 + d1;
    if (base + 3 < n) rowptr[base + 3] = eb + d0 + d1 + d2;
    if (t == 255) partials[b] = incl;
}

// merged scan2+scan3: every block redundantly scans the (<=256) partials in LDS
__global__ __launch_bounds__(256)
void scan23(int* __restrict__ rowptr, const int* __restrict__ partials,
            int* __restrict__ cursor, int n, int total, int nb) {
    __shared__ int lds[256];
    int t = threadIdx.x, b = blockIdx.x;
    lds[t] = (t < nb) ? partials[t] : 0;
    __syncthreads();
    for (int off = 1; off < 256; off <<= 1) {
        int v = (t >= off) ? lds[t - off] : 0;
        __syncthreads();
        lds[t] += v;
        __syncthreads();
    }
    int add = (b == 0) ? 0 : lds[b - 1];
    int base = b * 1024 + t * 4;
    #pragma unroll
    for (int j = 0; j < 4; ++j) {
        if (base + j < n) {
            int v = rowptr[base + j] + add;
            rowptr[base + j] = v;
            cursor[base + j] = v;
        }
    }
    if (b == 0 && t == 0) rowptr[n] = total;
}

__global__ __launch_bounds__(256)
void fill_csr(const int* __restrict__ e2o, const int* __restrict__ o2o,
              int* __restrict__ cursor, int* __restrict__ csr) {
    int i = blockIdx.x * 256 + threadIdx.x;
    if (i < N_EDGES) {
        int d = e2o[N_EDGES + i];
        int p = atomicAdd(&cursor[d], 1);
        csr[p] = e2o[i];
    } else if (i < 2 * N_EDGES) {
        int j = i - N_EDGES;
        int d = o2o[N_EDGES + j];
        int p = atomicAdd(&cursor[N_NODES + d], 1);
        csr[p] = o2o[j];
    }
}

// ---------- three W[512,512] fp32 -> Wt[n][k] bf16 in one dispatch ----------
__global__ __launch_bounds__(256)
void transpose3(const float* __restrict__ W0, const float* __restrict__ W1, const float* __restrict__ W2,
                unsigned short* __restrict__ T0, unsigned short* __restrict__ T1, unsigned short* __restrict__ T2) {
    __shared__ float tile[32][33];
    int z = blockIdx.z;
    const float* W = (z == 0) ? W0 : (z == 1) ? W1 : W2;
    unsigned short* T = (z == 0) ? T0 : (z == 1) ? T1 : T2;
    int bx = blockIdx.x, by = blockIdx.y;
    int t = threadIdx.x, tx = t & 31, ty = t >> 5;
    #pragma unroll
    for (int p = 0; p < 4; ++p) {
        int k = by * 32 + ty + p * 8;
        tile[ty + p * 8][tx] = W[(size_t)k * D + bx * 32 + tx];
    }
    __syncthreads();
    #pragma unroll
    for (int p = 0; p < 4; ++p) {
        int n = bx * 32 + ty + p * 8;
        T[(size_t)n * D + by * 32 + tx] = f2bf(tile[tx][ty + p * 8]);
    }
}

// ---------- x_o, x_e fp32 -> bf16 in one dispatch ----------
__global__ __launch_bounds__(256)
void convert2(const float4* __restrict__ x0, const float4* __restrict__ x1,
              uint2* __restrict__ y0, uint2* __restrict__ y1) {
    const int n4 = N_NODES * D / 4;
    int i = blockIdx.x * 256 + threadIdx.x;
    const float4* s; uint2* d; int j;
    if (i < n4) { s = x0; d = y0; j = i; }
    else { s = x1; d = y1; j = i - n4; }
    float4 v = s[j];
    uint2 o; o.x = pkbf(v.x, v.y); o.y = pkbf(v.z, v.w);
    d[j] = o;
}

// ---------- merged projection GEMMs + fused per-head attention dots ----------
// K-loop: 3-buffer LDS pipeline, prefetch depth 2, COUNTED vmcnt(4) so the
// just-issued tile's loads stay in flight ACROSS the barrier (T3+T4). Never
// drain vmcnt to 0 in the main loop. lgkmcnt(0) before the barrier closes the
// in-flight-ds_read vs gl_lds-write race; sched_barrier(0) pins the schedule.
__global__ __launch_bounds__(256)
void gemm_proj2(const unsigned short* __restrict__ A0, const unsigned short* __restrict__ A1,
                const unsigned short* __restrict__ Bt0, const unsigned short* __restrict__ Bt1,
                const float* __restrict__ b0, const float* __restrict__ b1,
                unsigned short* __restrict__ C0, unsigned short* __restrict__ C1,
                const float* __restrict__ at00, const float* __restrict__ at01, const float* __restrict__ at02,
                float* __restrict__ ao00, float* __restrict__ ao01, float* __restrict__ ao02,
                const float* __restrict__ at10, float* __restrict__ ao10)
{
    __shared__ __align__(16) unsigned short As[3][4096];   // [buf][8 subtiles of [16 rows][32 k]]
    __shared__ __align__(16) unsigned short Bs[3][4096];
    const int M = N_NODES;
    int lin = blockIdx.x;
    int half = (lin >= NBLK) ? 1 : 0;
    lin -= half * NBLK;
    int rblk, cblk; map_block(lin, rblk, cblk);
    const unsigned short* A  = half ? A1 : A0;
    const unsigned short* Bt = half ? Bt1 : Bt0;
    const float* bias        = half ? b1 : b0;
    unsigned short* C        = half ? C1 : C0;
    const int natt = half ? 1 : 3;
    const float* attA = half ? at10 : at00;
    const float* attB = at01;
    const float* attC = at02;
    float* aoA = half ? ao10 : ao00;
    float* aoB = ao01;
    float* aoC = ao02;

    const int tid = threadIdx.x, lane = tid & 63, wave = tid >> 6;
    const int rb = rblk * 128, cb = cblk * 128;
    const int wm = (wave >> 1) * 64, wn = (wave & 1) * 64;

    // staging: each wave fills subtiles {2w, 2w+1} of A and B.
    // lane l -> row (l&15) of subtile, k-chunk (l>>4)*8 elems; LDS dest = base + l*16B
    const unsigned short* agp[2]; const unsigned short* bgp[2];
    int sub[2];
    #pragma unroll
    for (int c = 0; c < 2; ++c) {
        int s = wave * 2 + c;
        sub[c] = s;
        int rA = rb + s * 16 + (lane & 15); if (rA > M - 1) rA = M - 1;
        agp[c] = A + (size_t)rA * D + (lane >> 4) * 8;
        int rB = cb + s * 16 + (lane & 15);
        bgp[c] = Bt + (size_t)rB * D + (lane >> 4) * 8;
    }

    f32x4 acc[4][4];
    #pragma unroll
    for (int i = 0; i < 4; ++i)
        #pragma unroll
        for (int j = 0; j < 4; ++j) acc[i][j] = (f32x4){0.f, 0.f, 0.f, 0.f};

    // prologue: stage tile0 -> buf0, tile1 -> buf1; wait tile0 only (tile1 stays in flight)
    #pragma unroll
    for (int c = 0; c < 2; ++c) {
        gl_lds16(agp[c], &As[0][sub[c] * 512]); agp[c] += 32;
        gl_lds16(bgp[c], &Bs[0][sub[c] * 512]); bgp[c] += 32;
    }
    #pragma unroll
    for (int c = 0; c < 2; ++c) {
        gl_lds16(agp[c], &As[1][sub[c] * 512]); agp[c] += 32;
        gl_lds16(bgp[c], &Bs[1][sub[c] * 512]); bgp[c] += 32;
    }
    asm volatile("s_waitcnt vmcnt(4)" ::: "memory");
    __builtin_amdgcn_s_barrier();

    // rotating buffers: R = read (tile k), M_ = in flight (tile k+1), P = prefetch dest (tile k+2)
    unsigned short *aR = As[0], *bR = Bs[0];
    unsigned short *aM = As[1], *bM = Bs[1];
    unsigned short *aP = As[2], *bP = Bs[2];

    for (int k = 0; k < 16; ++k) {
        bf16x8 af[4], bfr[4];
        #pragma unroll
        for (int mi = 0; mi < 4; ++mi) af[mi] = *(const bf16x8*)&aR[((wave >> 1) * 4 + mi) * 512 + lane * 8];
        #pragma unroll
        for (int ni = 0; ni < 4; ++ni) bfr[ni] = *(const bf16x8*)&bR[((wave & 1) * 4 + ni) * 512 + lane * 8];
        if (k < 14) {
            #pragma unroll
            for (int c = 0; c < 2; ++c) {
                gl_lds16(agp[c], &aP[sub[c] * 512]); agp[c] += 32;
                gl_lds16(bgp[c], &bP[sub[c] * 512]); bgp[c] += 32;
            }
        }
        #pragma unroll
        for (int mi = 0; mi < 4; ++mi)
            #pragma unroll
            for (int ni = 0; ni < 4; ++ni)
                acc[mi][ni] = __builtin_amdgcn_mfma_f32_16x16x32_bf16(af[mi], bfr[ni], acc[mi][ni], 0, 0, 0);
        __builtin_amdgcn_sched_barrier(0);
        if (k < 14) asm volatile("s_waitcnt vmcnt(4) lgkmcnt(0)" ::: "memory");
        else        asm volatile("s_waitcnt vmcnt(0) lgkmcnt(0)" ::: "memory");
        __builtin_amdgcn_s_barrier();
        unsigned short* t;
        t = aR; aR = aM; aM = aP; aP = t;
        t = bR; bR = bM; bM = bP; bP = t;
    }

    // epilogue: bias + bf16 store + per-head attention dots (this wave's 64 cols = one head)
    float bb[4], av0[4], av1[4], av2[4];
    const int head = (cb + wn) >> 6;
    #pragma unroll
    for (int ni = 0; ni < 4; ++ni) {
        int ci = ni * 16 + (lane & 15);
        bb[ni] = bias[cb + wn + ci];
        av0[ni] = attA[head * 64 + ci];
        if (natt > 1) { av1[ni] = attB[head * 64 + ci]; av2[ni] = attC[head * 64 + ci]; }
    }
    #pragma unroll
    for (int mi = 0; mi < 4; ++mi) {
        #pragma unroll
        for (int r = 0; r < 4; ++r) {
            int rg = rb + wm + mi * 16 + (lane >> 4) * 4 + r;
            bool ok = rg < M;
            float v[4];
            #pragma unroll
            for (int ni = 0; ni < 4; ++ni) v[ni] = acc[mi][ni][r] + bb[ni];
            if (ok) {
                size_t base = (size_t)rg * D + cb + wn + (lane & 15);
                #pragma unroll
                for (int ni = 0; ni < 4; ++ni) C[base + ni * 16] = f2bf(v[ni]);
            }
            float s0 = v[0] * av0[0] + v[1] * av0[1] + v[2] * av0[2] + v[3] * av0[3];
            float s1 = 0.f, s2 = 0.f;
            if (natt > 1) {
                s1 = v[0] * av1[0] + v[1] * av1[1] + v[2] * av1[2] + v[3] * av1[3];
                s2 = v[0] * av2[0] + v[1] * av2[1] + v[2] * av2[2] + v[3] * av2[3];
            }
            #pragma unroll
            for (int m2 = 1; m2 < 16; m2 <<= 1) {
                s0 += __shfl_xor(s0, m2);
                if (natt > 1) { s1 += __shfl_xor(s1, m2); s2 += __shfl_xor(s2, m2); }
            }
            if (ok && (lane & 15) == 0) {
                aoA[rg * H + head] = s0;
                if (natt > 1) { aoB[rg * H + head] = s1; aoC[rg * H + head] = s2; }
            }
        }
    }
}

// ---------- merged CSR aggregation (both metapaths): one wave per dst node ----------
__global__ __launch_bounds__(256)
void aggregate2(const int* __restrict__ rowptr, const int* __restrict__ csr,
                const float* __restrict__ aS0, const float* __restrict__ aD0, const unsigned short* __restrict__ hE,
                const float* __restrict__ aS1, const float* __restrict__ aD1, const unsigned short* __restrict__ hO,
                unsigned short* __restrict__ out0, unsigned short* __restrict__ out1)
{
    int gw = (blockIdx.x * 256 + threadIdx.x) >> 6;
    int lane = threadIdx.x & 63;
    if (gw >= 2 * N_NODES) return;
    int half = gw >= N_NODES;
    int node = gw - half * N_NODES;
    const float* a_src = half ? aS1 : aS0;
    const float* a_dst = half ? aD1 : aD0;
    const unsigned short* h = half ? hO : hE;
    unsigned short* out = half ? out1 : out0;

    int beg = rowptr[gw], end = rowptr[gw + 1];
    int hh = lane & 7;
    float adst = a_dst[node * H + hh];

    float amax = -1e30f;
    for (int p = beg; p < end; ++p) {
        int s = csr[p];
        float al = a_src[s * H + hh] + adst;
        al = (al >= 0.f) ? al : NEG_SLOPE * al;
        amax = fmaxf(amax, al);
    }
    float denom = 0.f;
    for (int p = beg; p < end; ++p) {
        int s = csr[p];
        float al = a_src[s * H + hh] + adst;
        al = (al >= 0.f) ? al : NEG_SLOPE * al;
        denom += expf(al - amax);
    }
    float inv = 1.f / (denom + 1e-16f);

    float acc[8] = {0.f, 0.f, 0.f, 0.f, 0.f, 0.f, 0.f, 0.f};
    for (int p = beg; p < end; ++p) {
        int s = csr[p];
        float al = a_src[s * H + hh] + adst;
        al = (al >= 0.f) ? al : NEG_SLOPE * al;
        float w = expf(al - amax) * inv;
        const unsigned short* hp = h + (size_t)s * D;
        #pragma unroll
        for (int h2 = 0; h2 < 8; ++h2) {
            float wh = __shfl(w, h2);
            acc[h2] += bf2f(hp[h2 * 64 + lane]) * wh;
        }
    }
    size_t base = (size_t)node * D;
    #pragma unroll
    for (int h2 = 0; h2 < 8; ++h2)
        out[base + h2 * 64 + lane] = f2bf(fmaxf(acc[h2], 0.f));
}

// ---------- merged column sums of both relu'd bf16 matrices ----------
__global__ __launch_bounds__(256)
void colsum2(const unsigned short* __restrict__ ob0, const unsigned short* __restrict__ ob1,
             float* __restrict__ colsum)
{
    __shared__ float red[512];
    int b = blockIdx.x;
    int half = b >= NBR;
    const unsigned short* ob = half ? ob1 : ob0;
    float* cs = colsum + half * 512;
    int t = threadIdx.x;
    int r0 = (b - half * NBR) * 128;
    int c8 = t & 63;
    float s[8] = {0.f, 0.f, 0.f, 0.f, 0.f, 0.f, 0.f, 0.f};
    for (int it = 0; it < 32; ++it) {
        int row = r0 + it * 4 + (t >> 6);
        if (row < N_NODES) {
            uint4 v = *((const uint4*)(ob + (size_t)row * D) + c8);
            s[0] += bf2f((unsigned short)(v.x & 0xFFFF)); s[1] += bf2f((unsigned short)(v.x >> 16));
            s[2] += bf2f((unsigned short)(v.y & 0xFFFF)); s[3] += bf2f((unsigned short)(v.y >> 16));
            s[4] += bf2f((unsigned short)(v.z & 0xFFFF)); s[5] += bf2f((unsigned short)(v.z >> 16));
            s[6] += bf2f((unsigned short)(v.w & 0xFFFF)); s[7] += bf2f((unsigned short)(v.w >> 16));
        }
    }
    red[t] = 0.f; red[t + 256] = 0.f;
    __syncthreads();
    #pragma unroll
    for (int j = 0; j < 8; ++j) atomicAdd(&red[c8 * 8 + j], s[j]);
    __syncthreads();
    atomicAdd(&cs[t & 511], red[t]);
    atomicAdd(&cs[(t + 256) & 511], red[t + 256]);
}

// ---------- merged semantic-K GEMMs: ksum[half][f] += sum_rows tanh((A@Wkl^T + b)[row,f]) ----------
__global__ __launch_bounds__(256)
void gemm_tanh2(const unsigned short* __restrict__ Ah0, const unsigned short* __restrict__ Ah1,
                const unsigned short* __restrict__ Bt, const float* __restrict__ bias,
                float* __restrict__ ksum)
{
    __shared__ __align__(16) unsigned short As[3][4096];
    __shared__ __align__(16) unsigned short Bs[3][4096];
    const int M = N_NODES;
    int lin = blockIdx.x;
    int half = (lin >= NBLK) ? 1 : 0;
    lin -= half * NBLK;
    int rblk, cblk; map_block(lin, rblk, cblk);
    const unsigned short* A = half ? Ah1 : Ah0;
    float* ks = ksum + half * 512;

    const int tid = threadIdx.x, lane = tid & 63, wave = tid >> 6;
    const int rb = rblk * 128, cb = cblk * 128;
    const int wm = (wave >> 1) * 64, wn = (wave & 1) * 64;

    const unsigned short* agp[2]; const unsigned short* bgp[2];
    int sub[2];
    #pragma unroll
    for (int c = 0; c < 2; ++c) {
        int s = wave * 2 + c;
        sub[c] = s;
        int rA = rb + s * 16 + (lane & 15); if (rA > M - 1) rA = M - 1;
        agp[c] = A + (size_t)rA * D + (lane >> 4) * 8;
        int rB = cb + s * 16 + (lane & 15);
        bgp[c] = Bt + (size_t)rB * D + (lane >> 4) * 8;
    }

    f32x4 acc[4][4];
    #pragma unroll
    for (int i = 0; i < 4; ++i)
        #pragma unroll
        for (int j = 0; j < 4; ++j) acc[i][j] = (f32x4){0.f, 0.f, 0.f, 0.f};

    // prologue: tile0 -> buf0, tile1 -> buf1; wait tile0 only
    #pragma unroll
    for (int c = 0; c < 2; ++c) {
        gl_lds16(agp[c], &As[0][sub[c] * 512]); agp[c] += 32;
        gl_lds16(bgp[c], &Bs[0][sub[c] * 512]); bgp[c] += 32;
    }
    #pragma unroll
    for (int c = 0; c < 2; ++c) {
        gl_lds16(agp[c], &As[1][sub[c] * 512]); agp[c] += 32;
        gl_lds16(bgp[c], &Bs[1][sub[c] * 512]); bgp[c] += 32;
    }
    asm volatile("s_waitcnt vmcnt(4)" ::: "memory");
    __builtin_amdgcn_s_barrier();

    unsigned short *aR = As[0], *bR = Bs[0];
    unsigned short *aM = As[1], *bM = Bs[1];
    unsigned short *aP = As[2], *bP = Bs[2];

    for (int k = 0; k < 16; ++k) {
        bf16x8 af[4], bfr[4];
        #pragma unroll
        for (int mi = 0; mi < 4; ++mi) af[mi] = *(const bf16x8*)&aR[((wave >> 1) * 4 + mi) * 512 + lane * 8];
        #pragma unroll
        for (int ni = 0; ni < 4; ++ni) bfr[ni] = *(const bf16x8*)&bR[((wave & 1) * 4 + ni) * 512 + lane * 8];
        if (k < 14) {
            #pragma unroll
            for (int c = 0; c < 2; ++c) {
                gl_lds16(agp[c], &aP[sub[c] * 512]); agp[c] += 32;
                gl_lds16(bgp[c], &bP[sub[c] * 512]); bgp[c] += 32;
            }
        }
        #pragma unroll
        for (int mi = 0; mi < 4; ++mi)
            #pragma unroll
            for (int ni = 0; ni < 4; ++ni)
                acc[mi][ni] = __builtin_amdgcn_mfma_f32_16x16x32_bf16(af[mi], bfr[ni], acc[mi][ni], 0, 0, 0);
        __builtin_amdgcn_sched_barrier(0);
        if (k < 14) asm volatile("s_waitcnt vmcnt(4) lgkmcnt(0)" ::: "memory");
        else        asm volatile("s_waitcnt vmcnt(0) lgkmcnt(0)" ::: "memory");
        __builtin_amdgcn_s_barrier();
        unsigned short* t;
        t = aR; aR = aM; aM = aP; aP = t;
        t = bR; bR = bM; bM = bP; bP = t;
    }

    float bb[4];
    #pragma unroll
    for (int ni = 0; ni < 4; ++ni) bb[ni] = bias[cb + wn + ni * 16 + (lane & 15)];
    float cs[4] = {0.f, 0.f, 0.f, 0.f};
    #pragma unroll
    for (int mi = 0; mi < 4; ++mi) {
        #pragma unroll
        for (int r = 0; r < 4; ++r) {
            int rg = rb + wm + mi * 16 + (lane >> 4) * 4 + r;
            if (rg < M) {
                #pragma unroll
                for (int ni = 0; ni < 4; ++ni)
                    cs[ni] += fast_tanh(acc[mi][ni][r] + bb[ni]);
            }
        }
    }
    __syncthreads();
    float* red = (float*)As;
    if (tid < 128) red[tid] = 0.f;
    __syncthreads();
    #pragma unroll
    for (int ni = 0; ni < 4; ++ni) atomicAdd(&red[wn + ni * 16 + (lane & 15)], cs[ni]);
    __syncthreads();
    if (tid < 128) atomicAdd(&ks[cb + tid], red[tid]);
}

// ---------- final semantic softmax + pool + linear ----------
__global__ __launch_bounds__(256)
void finalize(const float* __restrict__ ksum, const float* __restrict__ colsum,
              const float* __restrict__ q_sem, const float* __restrict__ lin_w,
              const float* __restrict__ lin_b, float* __restrict__ dout)
{
    __shared__ float red[256];
    __shared__ float semsh[2];
    int t = threadIdx.x;
    const float invN = 1.0f / (float)N_NODES;
    float p0 = ksum[t] * q_sem[t] + ksum[t + 256] * q_sem[t + 256];
    float p1 = ksum[512 + t] * q_sem[t] + ksum[512 + t + 256] * q_sem[t + 256];

    red[t] = p0; __syncthreads();
    for (int s = 128; s > 0; s >>= 1) { if (t < s) red[t] += red[t + s]; __syncthreads(); }
    float S0 = red[0]; __syncthreads();
    red[t] = p1; __syncthreads();
    for (int s = 128; s > 0; s >>= 1) { if (t < s) red[t] += red[t + s]; __syncthreads(); }
    float S1 = red[0]; __syncthreads();

    if (t == 0) {
        float a0 = S0 * invN, a1 = S1 * invN;
        float mx = fmaxf(a0, a1);
        float e0 = expf(a0 - mx), e1 = expf(a1 - mx);
        semsh[0] = e0 / (e0 + e1);
        semsh[1] = e1 / (e0 + e1);
    }
    __syncthreads();
    float sem0 = semsh[0], sem1 = semsh[1];

    float o0 = 0.f, o1 = 0.f;
    #pragma unroll
    for (int q = 0; q < 2; ++q) {
        int f = t + q * 256;
        float pooled = (sem0 * colsum[f] + sem1 * colsum[512 + f]) * invN;
        o0 += pooled * lin_w[f * 2 + 0];
        o1 += pooled * lin_w[f * 2 + 1];
    }
    red[t] = o0; __syncthreads();
    for (int s = 128; s > 0; s >>= 1) { if (t < s) red[t] += red[t + s]; __syncthreads(); }
    if (t == 0) dout[0] = red[0] + lin_b[0];
    __syncthreads();
    red[t] = o1; __syncthreads();
    for (int s = 128; s > 0; s >>= 1) { if (t < s) red[t] += red[t + s]; __syncthreads(); }
    if (t == 0) dout[1] = red[0] + lin_b[1];
}

extern "C" void kernel_launch(void* const* d_in, const int* in_sizes, int n_in,
                              void* d_out, int out_size, void* d_ws, size_t ws_size,
                              hipStream_t stream)
{
    const float* x_o    = (const float*)d_in[0];
    const float* x_e    = (const float*)d_in[1];
    const int*   e2o    = (const int*)d_in[2];
    const int*   o2o    = (const int*)d_in[3];
    const float* pow_   = (const float*)d_in[4];
    const float* pob    = (const float*)d_in[5];
    const float* pew    = (const float*)d_in[6];
    const float* peb    = (const float*)d_in[7];
    const float* as_e2o = (const float*)d_in[8];
    const float* ad_e2o = (const float*)d_in[9];
    const float* as_o2o = (const float*)d_in[10];
    const float* ad_o2o = (const float*)d_in[11];
    const float* klw    = (const float*)d_in[12];
    const float* klb    = (const float*)d_in[13];
    const float* qsem   = (const float*)d_in[14];
    const float* linw   = (const float*)d_in[15];
    const float* linb   = (const float*)d_in[16];

    char* ws = (char*)d_ws;
    size_t off = 0;
    auto alloc = [&](size_t bytes) { void* p = ws + off; off += (bytes + 255) & ~(size_t)255; return p; };

    unsigned short* xbf_o = (unsigned short*)alloc((size_t)N_NODES * D * 2);
    unsigned short* xbf_e = (unsigned short*)alloc((size_t)N_NODES * D * 2);
    unsigned short* h_o   = (unsigned short*)alloc((size_t)N_NODES * D * 2);
    unsigned short* h_e   = (unsigned short*)alloc((size_t)N_NODES * D * 2);
    unsigned short* obf0  = (unsigned short*)alloc((size_t)N_NODES * D * 2);
    unsigned short* obf1  = (unsigned short*)alloc((size_t)N_NODES * D * 2);
    unsigned short* wt_po = (unsigned short*)alloc((size_t)D * D * 2);
    unsigned short* wt_pe = (unsigned short*)alloc((size_t)D * D * 2);
    unsigned short* wt_kl = (unsigned short*)alloc((size_t)D * D * 2);
    float* aS0 = (float*)alloc((size_t)N_NODES * H * 4);
    float* aD0 = (float*)alloc((size_t)N_NODES * H * 4);
    float* aS1 = (float*)alloc((size_t)N_NODES * H * 4);
    float* aD1 = (float*)alloc((size_t)N_NODES * H * 4);
    // contiguous zeroed region: colsum[1024] | ksum[1024] | deg[2N]
    int* misc    = (int*)alloc((2048 + 2 * N_NODES) * 4);
    float* colsum = (float*)misc;
    float* ksum   = colsum + 1024;
    int* deg      = misc + 2048;
    int* cursor  = (int*)alloc(2 * N_NODES * 4);
    int* rowptr  = (int*)alloc((2 * N_NODES + 1) * 4);
    int* partials= (int*)alloc(256 * 4);
    int* csr     = (int*)alloc(2 * N_EDGES * 4);

    const int NSC = 2 * N_NODES;
    const int NB1 = (NSC + 1023) / 1024;              // 196
    const int EH  = (2 * N_EDGES + 255) / 256;        // 1172

    hipMemsetAsync(misc, 0, (size_t)(2048 + 2 * N_NODES) * 4, stream);

    // CSR build
    hist_edges<<<EH, 256, 0, stream>>>(e2o, o2o, deg);
    scan1<<<NB1, 256, 0, stream>>>(deg, rowptr, partials, NSC);
    scan23<<<NB1, 256, 0, stream>>>(rowptr, partials, cursor, NSC, 2 * N_EDGES, NB1);
    fill_csr<<<EH, 256, 0, stream>>>(e2o, o2o, cursor, csr);

    // weights -> bf16 W^T (one dispatch), inputs -> bf16 (one dispatch)
    transpose3<<<dim3(16, 16, 3), 256, 0, stream>>>(pow_, pew, klw, wt_po, wt_pe, wt_kl);
    convert2<<<(2 * N_NODES * D / 4) / 256, 256, 0, stream>>>(
        (const float4*)x_o, (const float4*)x_e, (uint2*)xbf_o, (uint2*)xbf_e);

    // merged projections + fused attention dots
    gemm_proj2<<<2 * NBLK, 256, 0, stream>>>(
        xbf_o, xbf_e, wt_po, wt_pe, pob, peb, h_o, h_e,
        ad_e2o, as_o2o, ad_o2o, aD0, aS1, aD1,
        as_e2o, aS0);

    // merged aggregation, column sums, semantic-K GEMMs
    aggregate2<<<(2 * N_NODES * 64) / 256, 256, 0, stream>>>(
        rowptr, csr, aS0, aD0, h_e, aS1, aD1, h_o, obf0, obf1);
    colsum2<<<2 * NBR, 256, 0, stream>>>(obf0, obf1, colsum);
    gemm_tanh2<<<2 * NBLK, 256, 0, stream>>>(obf0, obf1, wt_kl, klb, ksum);

    finalize<<<1, 256, 0, stream>>>(ksum, colsum, qsem, linw, linb, (float*)d_out);
}

// Round 4
// 1145.565 us; speedup vs baseline: 1.0948x; 1.0360x over previous
//
#include <hip/hip_runtime.h>
#include <math.h>

#define N_NODES 100000
#define N_EDGES 150000
#define D 512
#define H 8
#define NEG_SLOPE 0.2f
#define NBR 782           // row blocks of 128 (colsum2)
#define NBRG 391          // GEMM row blocks of 256 over 100000 rows
#define NBLKG (NBRG * 4)  // 1564 blocks per GEMM half

typedef __attribute__((ext_vector_type(8))) short bf16x8;
typedef __attribute__((ext_vector_type(4))) float f32x4;

// ---------- helpers ----------
__device__ __forceinline__ float bf2f(unsigned short u) { return __uint_as_float(((unsigned int)u) << 16); }
__device__ __forceinline__ unsigned short f2bf(float f) {
    unsigned int u = __float_as_uint(f);
    unsigned int r = u + 0x7FFFu + ((u >> 16) & 1u);
    return (unsigned short)(r >> 16);
}
__device__ __forceinline__ unsigned int pkbf(float a, float b) {
    unsigned int ua = __float_as_uint(a) + 0x8000u;
    unsigned int ub = __float_as_uint(b) + 0x8000u;
    return (ua >> 16) | (ub & 0xFFFF0000u);
}
__device__ __forceinline__ void gl_lds16(const void* g, void* l) {
    __builtin_amdgcn_global_load_lds((const __attribute__((address_space(1))) void*)g,
                                     (__attribute__((address_space(3))) void*)l, 16, 0, 0);
}
// fast tanh: 1 - 2/(e^{2x}+1)
__device__ __forceinline__ float fast_tanh(float x) {
    float e = __expf(2.0f * x);
    float r;
    asm("v_rcp_f32 %0, %1" : "=v"(r) : "v"(e + 1.0f));
    return 1.0f - 2.0f * r;
}
// XCD-aware swizzle for the GEMM grid (NBRG row blocks x 4 col blocks):
// groups of 32 linear ids = 8 row-blocks x 4 col-blocks; id%8 (XCD on
// round-robin dispatch) = row-block within group -> the 4 col tiles of one
// row-block share an XCD -> A rows fetched once per XCD L2.
__device__ __forceinline__ void map_block(int lin, int& rblk, int& cblk) {
    int g = lin >> 5;
    if (g < (NBRG >> 3)) { rblk = g * 8 + (lin & 7); cblk = (lin >> 3) & 3; }
    else { int idx = lin - (NBRG >> 3) * 32; rblk = (NBRG & ~7) + (idx >> 2); cblk = idx & 3; }
}

// ---------- CSR build ----------
__global__ __launch_bounds__(256)
void hist_edges(const int* __restrict__ e2o, const int* __restrict__ o2o, int* __restrict__ deg) {
    int i = blockIdx.x * 256 + threadIdx.x;
    if (i < N_EDGES) atomicAdd(&deg[e2o[N_EDGES + i]], 1);
    else if (i < 2 * N_EDGES) atomicAdd(&deg[N_NODES + o2o[N_EDGES + (i - N_EDGES)]], 1);
}

__global__ __launch_bounds__(256)
void scan1(const int* __restrict__ deg, int* __restrict__ rowptr, int* __restrict__ partials, int n) {
    __shared__ int lds[256];
    int t = threadIdx.x, b = blockIdx.x;
    int base = b * 1024 + t * 4;
    int d0 = (base + 0 < n) ? deg[base + 0] : 0;
    int d1 = (base + 1 < n) ? deg[base + 1] : 0;
    int d2 = (base + 2 < n) ? deg[base + 2] : 0;
    int d3 = (base + 3 < n) ? deg[base + 3] : 0;
    int s = d0 + d1 + d2 + d3;
    lds[t] = s;
    __syncthreads();
    for (int off = 1; off < 256; off <<= 1) {
        int v = (t >= off) ? lds[t - off] : 0;
        __syncthreads();
        lds[t] += v;
        __syncthreads();
    }
    int incl = lds[t];
    int eb = incl - s;
    if (base + 0 < n) rowptr[base + 0] = eb;
    if (base + 1 < n) rowptr[base + 1] = eb + d0;
    if (base + 2 < n) rowptr[base + 2] = eb + d0 + d1;
    if (base + 3 < n) rowptr[base + 3] = eb + d0 + d1 + d2;
    if (t == 255) partials[b] = incl;
}

// merged scan2+scan3: every block redundantly scans the (<=256) partials in LDS
__global__ __launch_bounds__(256)
void scan23(int* __restrict__ rowptr, const int* __restrict__ partials,
            int* __restrict__ cursor, int n, int total, int nb) {
    __shared__ int lds[256];
    int t = threadIdx.x, b = blockIdx.x;
    lds[t] = (t < nb) ? partials[t] : 0;
    __syncthreads();
    for (int off = 1; off < 256; off <<= 1) {
        int v = (t >= off) ? lds[t - off] : 0;
        __syncthreads();
        lds[t] += v;
        __syncthreads();
    }
    int add = (b == 0) ? 0 : lds[b - 1];
    int base = b * 1024 + t * 4;
    #pragma unroll
    for (int j = 0; j < 4; ++j) {
        if (base + j < n) {
            int v = rowptr[base + j] + add;
            rowptr[base + j] = v;
            cursor[base + j] = v;
        }
    }
    if (b == 0 && t == 0) rowptr[n] = total;
}

__global__ __launch_bounds__(256)
void fill_csr(const int* __restrict__ e2o, const int* __restrict__ o2o,
              int* __restrict__ cursor, int* __restrict__ csr) {
    int i = blockIdx.x * 256 + threadIdx.x;
    if (i < N_EDGES) {
        int d = e2o[N_EDGES + i];
        int p = atomicAdd(&cursor[d], 1);
        csr[p] = e2o[i];
    } else if (i < 2 * N_EDGES) {
        int j = i - N_EDGES;
        int d = o2o[N_EDGES + j];
        int p = atomicAdd(&cursor[N_NODES + d], 1);
        csr[p] = o2o[j];
    }
}

// ---------- three W[512,512] fp32 -> Wt[n][k] bf16 in one dispatch ----------
__global__ __launch_bounds__(256)
void transpose3(const float* __restrict__ W0, const float* __restrict__ W1, const float* __restrict__ W2,
                unsigned short* __restrict__ T0, unsigned short* __restrict__ T1, unsigned short* __restrict__ T2) {
    __shared__ float tile[32][33];
    int z = blockIdx.z;
    const float* W = (z == 0) ? W0 : (z == 1) ? W1 : W2;
    unsigned short* T = (z == 0) ? T0 : (z == 1) ? T1 : T2;
    int bx = blockIdx.x, by = blockIdx.y;
    int t = threadIdx.x, tx = t & 31, ty = t >> 5;
    #pragma unroll
    for (int p = 0; p < 4; ++p) {
        int k = by * 32 + ty + p * 8;
        tile[ty + p * 8][tx] = W[(size_t)k * D + bx * 32 + tx];
    }
    __syncthreads();
    #pragma unroll
    for (int p = 0; p < 4; ++p) {
        int n = bx * 32 + ty + p * 8;
        T[(size_t)n * D + by * 32 + tx] = f2bf(tile[tx][ty + p * 8]);
    }
}

// ---------- x_o, x_e fp32 -> bf16 in one dispatch ----------
__global__ __launch_bounds__(256)
void convert2(const float4* __restrict__ x0, const float4* __restrict__ x1,
              uint2* __restrict__ y0, uint2* __restrict__ y1) {
    const int n4 = N_NODES * D / 4;
    int i = blockIdx.x * 256 + threadIdx.x;
    const float4* s; uint2* d; int j;
    if (i < n4) { s = x0; d = y0; j = i; }
    else { s = x1; d = y1; j = i - n4; }
    float4 v = s[j];
    uint2 o; o.x = pkbf(v.x, v.y); o.y = pkbf(v.z, v.w);
    d[j] = o;
}

// ---------- merged projection GEMMs + fused per-head attention dots ----------
// 256x128 tile, 4 waves, each wave owns 128x64 (acc[8][4]) -> 2x MFMA work
// per barrier/latency chain vs 128x128. 3-stage LDS (72KB, 2 blocks/CU),
// counted vmcnt(6): prefetched tile's 6 loads stay in flight across barriers.
__global__ __launch_bounds__(256, 2)
void gemm_proj2(const unsigned short* __restrict__ A0, const unsigned short* __restrict__ A1,
                const unsigned short* __restrict__ Bt0, const unsigned short* __restrict__ Bt1,
                const float* __restrict__ b0, const float* __restrict__ b1,
                unsigned short* __restrict__ C0, unsigned short* __restrict__ C1,
                const float* __restrict__ at00, const float* __restrict__ at01, const float* __restrict__ at02,
                float* __restrict__ ao00, float* __restrict__ ao01, float* __restrict__ ao02,
                const float* __restrict__ at10, float* __restrict__ ao10)
{
    __shared__ __align__(16) unsigned short As[3][8192];   // 16 subtiles of [16 rows][32 k]
    __shared__ __align__(16) unsigned short Bs[3][4096];   // 8 subtiles
    const int M = N_NODES;
    int lin = blockIdx.x;
    int half = (lin >= NBLKG) ? 1 : 0;
    lin -= half * NBLKG;
    int rblk, cblk; map_block(lin, rblk, cblk);
    const unsigned short* A  = half ? A1 : A0;
    const unsigned short* Bt = half ? Bt1 : Bt0;
    const float* bias        = half ? b1 : b0;
    unsigned short* C        = half ? C1 : C0;
    const int natt = half ? 1 : 3;
    const float* attA = half ? at10 : at00;
    const float* attB = at01;
    const float* attC = at02;
    float* aoA = half ? ao10 : ao00;
    float* aoB = ao01;
    float* aoC = ao02;

    const int tid = threadIdx.x, lane = tid & 63, wave = tid >> 6;
    const int rb = rblk * 256, cb = cblk * 128;
    const int wm = (wave >> 1) * 128, wn = (wave & 1) * 64;

    // staging: wave fills A subtiles {4w..4w+3} and B subtiles {2w,2w+1}.
    // lane l -> row (l&15) of subtile, k-chunk (l>>4)*8; LDS dest = base + l*16B
    const unsigned short* agp[4]; const unsigned short* bgp[2];
    int asub[4], bsub[2];
    #pragma unroll
    for (int c = 0; c < 4; ++c) {
        int s = wave * 4 + c;
        asub[c] = s;
        int rA = rb + s * 16 + (lane & 15); if (rA > M - 1) rA = M - 1;
        agp[c] = A + (size_t)rA * D + (lane >> 4) * 8;
    }
    #pragma unroll
    for (int c = 0; c < 2; ++c) {
        int s = wave * 2 + c;
        bsub[c] = s;
        int rB = cb + s * 16 + (lane & 15);
        bgp[c] = Bt + (size_t)rB * D + (lane >> 4) * 8;
    }

    f32x4 acc[8][4];
    #pragma unroll
    for (int i = 0; i < 8; ++i)
        #pragma unroll
        for (int j = 0; j < 4; ++j) acc[i][j] = (f32x4){0.f, 0.f, 0.f, 0.f};

    // prologue: stage tile0 -> buf0, tile1 -> buf1; wait tile0 only
    #pragma unroll
    for (int c = 0; c < 4; ++c) { gl_lds16(agp[c], &As[0][asub[c] * 512]); agp[c] += 32; }
    #pragma unroll
    for (int c = 0; c < 2; ++c) { gl_lds16(bgp[c], &Bs[0][bsub[c] * 512]); bgp[c] += 32; }
    #pragma unroll
    for (int c = 0; c < 4; ++c) { gl_lds16(agp[c], &As[1][asub[c] * 512]); agp[c] += 32; }
    #pragma unroll
    for (int c = 0; c < 2; ++c) { gl_lds16(bgp[c], &Bs[1][bsub[c] * 512]); bgp[c] += 32; }
    asm volatile("s_waitcnt vmcnt(6)" ::: "memory");
    __builtin_amdgcn_s_barrier();

    unsigned short *aR = As[0], *bR = Bs[0];
    unsigned short *aM = As[1], *bM = Bs[1];
    unsigned short *aP = As[2], *bP = Bs[2];

    for (int k = 0; k < 16; ++k) {
        // issue prefetch FIRST (issue-early), safe: P was finished-reading
        // before the barrier that started this iteration.
        if (k < 14) {
            #pragma unroll
            for (int c = 0; c < 4; ++c) { gl_lds16(agp[c], &aP[asub[c] * 512]); agp[c] += 32; }
            #pragma unroll
            for (int c = 0; c < 2; ++c) { gl_lds16(bgp[c], &bP[bsub[c] * 512]); bgp[c] += 32; }
        }
        bf16x8 af[8], bfr[4];
        #pragma unroll
        for (int mi = 0; mi < 8; ++mi) af[mi] = *(const bf16x8*)&aR[((wave >> 1) * 8 + mi) * 512 + lane * 8];
        #pragma unroll
        for (int ni = 0; ni < 4; ++ni) bfr[ni] = *(const bf16x8*)&bR[((wave & 1) * 4 + ni) * 512 + lane * 8];
        #pragma unroll
        for (int mi = 0; mi < 8; ++mi)
            #pragma unroll
            for (int ni = 0; ni < 4; ++ni)
                acc[mi][ni] = __builtin_amdgcn_mfma_f32_16x16x32_bf16(af[mi], bfr[ni], acc[mi][ni], 0, 0, 0);
        __builtin_amdgcn_sched_barrier(0);
        if (k < 14) asm volatile("s_waitcnt vmcnt(6) lgkmcnt(0)" ::: "memory");
        else        asm volatile("s_waitcnt vmcnt(0) lgkmcnt(0)" ::: "memory");
        __builtin_amdgcn_s_barrier();
        unsigned short* t;
        t = aR; aR = aM; aM = aP; aP = t;
        t = bR; bR = bM; bM = bP; bP = t;
    }

    // epilogue: bias + bf16 store + per-head attention dots (wave's 64 cols = one head)
    float bb[4], av0[4], av1[4], av2[4];
    const int head = (cb + wn) >> 6;
    #pragma unroll
    for (int ni = 0; ni < 4; ++ni) {
        int ci = ni * 16 + (lane & 15);
        bb[ni] = bias[cb + wn + ci];
        av0[ni] = attA[head * 64 + ci];
        if (natt > 1) { av1[ni] = attB[head * 64 + ci]; av2[ni] = attC[head * 64 + ci]; }
    }
    #pragma unroll
    for (int mi = 0; mi < 8; ++mi) {
        #pragma unroll
        for (int r = 0; r < 4; ++r) {
            int rg = rb + wm + mi * 16 + (lane >> 4) * 4 + r;
            bool ok = rg < M;
            float v[4];
            #pragma unroll
            for (int ni = 0; ni < 4; ++ni) v[ni] = acc[mi][ni][r] + bb[ni];
            if (ok) {
                size_t base = (size_t)rg * D + cb + wn + (lane & 15);
                #pragma unroll
                for (int ni = 0; ni < 4; ++ni) C[base + ni * 16] = f2bf(v[ni]);
            }
            float s0 = v[0] * av0[0] + v[1] * av0[1] + v[2] * av0[2] + v[3] * av0[3];
            float s1 = 0.f, s2 = 0.f;
            if (natt > 1) {
                s1 = v[0] * av1[0] + v[1] * av1[1] + v[2] * av1[2] + v[3] * av1[3];
                s2 = v[0] * av2[0] + v[1] * av2[1] + v[2] * av2[2] + v[3] * av2[3];
            }
            #pragma unroll
            for (int m2 = 1; m2 < 16; m2 <<= 1) {
                s0 += __shfl_xor(s0, m2);
                if (natt > 1) { s1 += __shfl_xor(s1, m2); s2 += __shfl_xor(s2, m2); }
            }
            if (ok && (lane & 15) == 0) {
                aoA[rg * H + head] = s0;
                if (natt > 1) { aoB[rg * H + head] = s1; aoC[rg * H + head] = s2; }
            }
        }
    }
}

// ---------- merged CSR aggregation (both metapaths): one wave per dst node ----------
__global__ __launch_bounds__(256)
void aggregate2(const int* __restrict__ rowptr, const int* __restrict__ csr,
                const float* __restrict__ aS0, const float* __restrict__ aD0, const unsigned short* __restrict__ hE,
                const float* __restrict__ aS1, const float* __restrict__ aD1, const unsigned short* __restrict__ hO,
                unsigned short* __restrict__ out0, unsigned short* __restrict__ out1)
{
    int gw = (blockIdx.x * 256 + threadIdx.x) >> 6;
    int lane = threadIdx.x & 63;
    if (gw >= 2 * N_NODES) return;
    int half = gw >= N_NODES;
    int node = gw - half * N_NODES;
    const float* a_src = half ? aS1 : aS0;
    const float* a_dst = half ? aD1 : aD0;
    const unsigned short* h = half ? hO : hE;
    unsigned short* out = half ? out1 : out0;

    int beg = rowptr[gw], end = rowptr[gw + 1];
    int hh = lane & 7;
    float adst = a_dst[node * H + hh];

    float amax = -1e30f;
    for (int p = beg; p < end; ++p) {
        int s = csr[p];
        float al = a_src[s * H + hh] + adst;
        al = (al >= 0.f) ? al : NEG_SLOPE * al;
        amax = fmaxf(amax, al);
    }
    float denom = 0.f;
    for (int p = beg; p < end; ++p) {
        int s = csr[p];
        float al = a_src[s * H + hh] + adst;
        al = (al >= 0.f) ? al : NEG_SLOPE * al;
        denom += expf(al - amax);
    }
    float inv = 1.f / (denom + 1e-16f);

    float acc[8] = {0.f, 0.f, 0.f, 0.f, 0.f, 0.f, 0.f, 0.f};
    for (int p = beg; p < end; ++p) {
        int s = csr[p];
        float al = a_src[s * H + hh] + adst;
        al = (al >= 0.f) ? al : NEG_SLOPE * al;
        float w = expf(al - amax) * inv;
        const unsigned short* hp = h + (size_t)s * D;
        #pragma unroll
        for (int h2 = 0; h2 < 8; ++h2) {
            float wh = __shfl(w, h2);
            acc[h2] += bf2f(hp[h2 * 64 + lane]) * wh;
        }
    }
    size_t base = (size_t)node * D;
    #pragma unroll
    for (int h2 = 0; h2 < 8; ++h2)
        out[base + h2 * 64 + lane] = f2bf(fmaxf(acc[h2], 0.f));
}

// ---------- merged column sums of both relu'd bf16 matrices ----------
__global__ __launch_bounds__(256)
void colsum2(const unsigned short* __restrict__ ob0, const unsigned short* __restrict__ ob1,
             float* __restrict__ colsum)
{
    __shared__ float red[512];
    int b = blockIdx.x;
    int half = b >= NBR;
    const unsigned short* ob = half ? ob1 : ob0;
    float* cs = colsum + half * 512;
    int t = threadIdx.x;
    int r0 = (b - half * NBR) * 128;
    int c8 = t & 63;
    float s[8] = {0.f, 0.f, 0.f, 0.f, 0.f, 0.f, 0.f, 0.f};
    for (int it = 0; it < 32; ++it) {
        int row = r0 + it * 4 + (t >> 6);
        if (row < N_NODES) {
            uint4 v = *((const uint4*)(ob + (size_t)row * D) + c8);
            s[0] += bf2f((unsigned short)(v.x & 0xFFFF)); s[1] += bf2f((unsigned short)(v.x >> 16));
            s[2] += bf2f((unsigned short)(v.y & 0xFFFF)); s[3] += bf2f((unsigned short)(v.y >> 16));
            s[4] += bf2f((unsigned short)(v.z & 0xFFFF)); s[5] += bf2f((unsigned short)(v.z >> 16));
            s[6] += bf2f((unsigned short)(v.w & 0xFFFF)); s[7] += bf2f((unsigned short)(v.w >> 16));
        }
    }
    red[t] = 0.f; red[t + 256] = 0.f;
    __syncthreads();
    #pragma unroll
    for (int j = 0; j < 8; ++j) atomicAdd(&red[c8 * 8 + j], s[j]);
    __syncthreads();
    atomicAdd(&cs[t & 511], red[t]);
    atomicAdd(&cs[(t + 256) & 511], red[t + 256]);
}

// ---------- merged semantic-K GEMMs: ksum[half][f] += sum_rows tanh((A@Wkl^T + b)[row,f]) ----------
__global__ __launch_bounds__(256, 2)
void gemm_tanh2(const unsigned short* __restrict__ Ah0, const unsigned short* __restrict__ Ah1,
                const unsigned short* __restrict__ Bt, const float* __restrict__ bias,
                float* __restrict__ ksum)
{
    __shared__ __align__(16) unsigned short As[3][8192];
    __shared__ __align__(16) unsigned short Bs[3][4096];
    const int M = N_NODES;
    int lin = blockIdx.x;
    int half = (lin >= NBLKG) ? 1 : 0;
    lin -= half * NBLKG;
    int rblk, cblk; map_block(lin, rblk, cblk);
    const unsigned short* A = half ? Ah1 : Ah0;
    float* ks = ksum + half * 512;

    const int tid = threadIdx.x, lane = tid & 63, wave = tid >> 6;
    const int rb = rblk * 256, cb = cblk * 128;
    const int wm = (wave >> 1) * 128, wn = (wave & 1) * 64;

    const unsigned short* agp[4]; const unsigned short* bgp[2];
    int asub[4], bsub[2];
    #pragma unroll
    for (int c = 0; c < 4; ++c) {
        int s = wave * 4 + c;
        asub[c] = s;
        int rA = rb + s * 16 + (lane & 15); if (rA > M - 1) rA = M - 1;
        agp[c] = A + (size_t)rA * D + (lane >> 4) * 8;
    }
    #pragma unroll
    for (int c = 0; c < 2; ++c) {
        int s = wave * 2 + c;
        bsub[c] = s;
        int rB = cb + s * 16 + (lane & 15);
        bgp[c] = Bt + (size_t)rB * D + (lane >> 4) * 8;
    }

    f32x4 acc[8][4];
    #pragma unroll
    for (int i = 0; i < 8; ++i)
        #pragma unroll
        for (int j = 0; j < 4; ++j) acc[i][j] = (f32x4){0.f, 0.f, 0.f, 0.f};

    #pragma unroll
    for (int c = 0; c < 4; ++c) { gl_lds16(agp[c], &As[0][asub[c] * 512]); agp[c] += 32; }
    #pragma unroll
    for (int c = 0; c < 2; ++c) { gl_lds16(bgp[c], &Bs[0][bsub[c] * 512]); bgp[c] += 32; }
    #pragma unroll
    for (int c = 0; c < 4; ++c) { gl_lds16(agp[c], &As[1][asub[c] * 512]); agp[c] += 32; }
    #pragma unroll
    for (int c = 0; c < 2; ++c) { gl_lds16(bgp[c], &Bs[1][bsub[c] * 512]); bgp[c] += 32; }
    asm volatile("s_waitcnt vmcnt(6)" ::: "memory");
    __builtin_amdgcn_s_barrier();

    unsigned short *aR = As[0], *bR = Bs[0];
    unsigned short *aM = As[1], *bM = Bs[1];
    unsigned short *aP = As[2], *bP = Bs[2];

    for (int k = 0; k < 16; ++k) {
        if (k < 14) {
            #pragma unroll
            for (int c = 0; c < 4; ++c) { gl_lds16(agp[c], &aP[asub[c] * 512]); agp[c] += 32; }
            #pragma unroll
            for (int c = 0; c < 2; ++c) { gl_lds16(bgp[c], &bP[bsub[c] * 512]); bgp[c] += 32; }
        }
        bf16x8 af[8], bfr[4];
        #pragma unroll
        for (int mi = 0; mi < 8; ++mi) af[mi] = *(const bf16x8*)&aR[((wave >> 1) * 8 + mi) * 512 + lane * 8];
        #pragma unroll
        for (int ni = 0; ni < 4; ++ni) bfr[ni] = *(const bf16x8*)&bR[((wave & 1) * 4 + ni) * 512 + lane * 8];
        #pragma unroll
        for (int mi = 0; mi < 8; ++mi)
            #pragma unroll
            for (int ni = 0; ni < 4; ++ni)
                acc[mi][ni] = __builtin_amdgcn_mfma_f32_16x16x32_bf16(af[mi], bfr[ni], acc[mi][ni], 0, 0, 0);
        __builtin_amdgcn_sched_barrier(0);
        if (k < 14) asm volatile("s_waitcnt vmcnt(6) lgkmcnt(0)" ::: "memory");
        else        asm volatile("s_waitcnt vmcnt(0) lgkmcnt(0)" ::: "memory");
        __builtin_amdgcn_s_barrier();
        unsigned short* t;
        t = aR; aR = aM; aM = aP; aP = t;
        t = bR; bR = bM; bM = bP; bP = t;
    }

    float bb[4];
    #pragma unroll
    for (int ni = 0; ni < 4; ++ni) bb[ni] = bias[cb + wn + ni * 16 + (lane & 15)];
    float cs[4] = {0.f, 0.f, 0.f, 0.f};
    #pragma unroll
    for (int mi = 0; mi < 8; ++mi) {
        #pragma unroll
        for (int r = 0; r < 4; ++r) {
            int rg = rb + wm + mi * 16 + (lane >> 4) * 4 + r;
            if (rg < M) {
                #pragma unroll
                for (int ni = 0; ni < 4; ++ni)
                    cs[ni] += fast_tanh(acc[mi][ni][r] + bb[ni]);
            }
        }
    }
    __syncthreads();
    float* red = (float*)As;
    if (tid < 128) red[tid] = 0.f;
    __syncthreads();
    #pragma unroll
    for (int ni = 0; ni < 4; ++ni) atomicAdd(&red[wn + ni * 16 + (lane & 15)], cs[ni]);
    __syncthreads();
    if (tid < 128) atomicAdd(&ks[cb + tid], red[tid]);
}

// ---------- final semantic softmax + pool + linear ----------
__global__ __launch_bounds__(256)
void finalize(const float* __restrict__ ksum, const float* __restrict__ colsum,
              const float* __restrict__ q_sem, const float* __restrict__ lin_w,
              const float* __restrict__ lin_b, float* __restrict__ dout)
{
    __shared__ float red[256];
    __shared__ float semsh[2];
    int t = threadIdx.x;
    const float invN = 1.0f / (float)N_NODES;
    float p0 = ksum[t] * q_sem[t] + ksum[t + 256] * q_sem[t + 256];
    float p1 = ksum[512 + t] * q_sem[t] + ksum[512 + t + 256] * q_sem[t + 256];

    red[t] = p0; __syncthreads();
    for (int s = 128; s > 0; s >>= 1) { if (t < s) red[t] += red[t + s]; __syncthreads(); }
    float S0 = red[0]; __syncthreads();
    red[t] = p1; __syncthreads();
    for (int s = 128; s > 0; s >>= 1) { if (t < s) red[t] += red[t + s]; __syncthreads(); }
    float S1 = red[0]; __syncthreads();

    if (t == 0) {
        float a0 = S0 * invN, a1 = S1 * invN;
        float mx = fmaxf(a0, a1);
        float e0 = expf(a0 - mx), e1 = expf(a1 - mx);
        semsh[0] = e0 / (e0 + e1);
        semsh[1] = e1 / (e0 + e1);
    }
    __syncthreads();
    float sem0 = semsh[0], sem1 = semsh[1];

    float o0 = 0.f, o1 = 0.f;
    #pragma unroll
    for (int q = 0; q < 2; ++q) {
        int f = t + q * 256;
        float pooled = (sem0 * colsum[f] + sem1 * colsum[512 + f]) * invN;
        o0 += pooled * lin_w[f * 2 + 0];
        o1 += pooled * lin_w[f * 2 + 1];
    }
    red[t] = o0; __syncthreads();
    for (int s = 128; s > 0; s >>= 1) { if (t < s) red[t] += red[t + s]; __syncthreads(); }
    if (t == 0) dout[0] = red[0] + lin_b[0];
    __syncthreads();
    red[t] = o1; __syncthreads();
    for (int s = 128; s > 0; s >>= 1) { if (t < s) red[t] += red[t + s]; __syncthreads(); }
    if (t == 0) dout[1] = red[0] + lin_b[1];
}

extern "C" void kernel_launch(void* const* d_in, const int* in_sizes, int n_in,
                              void* d_out, int out_size, void* d_ws, size_t ws_size,
                              hipStream_t stream)
{
    const float* x_o    = (const float*)d_in[0];
    const float* x_e    = (const float*)d_in[1];
    const int*   e2o    = (const int*)d_in[2];
    const int*   o2o    = (const int*)d_in[3];
    const float* pow_   = (const float*)d_in[4];
    const float* pob    = (const float*)d_in[5];
    const float* pew    = (const float*)d_in[6];
    const float* peb    = (const float*)d_in[7];
    const float* as_e2o = (const float*)d_in[8];
    const float* ad_e2o = (const float*)d_in[9];
    const float* as_o2o = (const float*)d_in[10];
    const float* ad_o2o = (const float*)d_in[11];
    const float* klw    = (const float*)d_in[12];
    const float* klb    = (const float*)d_in[13];
    const float* qsem   = (const float*)d_in[14];
    const float* linw   = (const float*)d_in[15];
    const float* linb   = (const float*)d_in[16];

    char* ws = (char*)d_ws;
    size_t off = 0;
    auto alloc = [&](size_t bytes) { void* p = ws + off; off += (bytes + 255) & ~(size_t)255; return p; };

    unsigned short* xbf_o = (unsigned short*)alloc((size_t)N_NODES * D * 2);
    unsigned short* xbf_e = (unsigned short*)alloc((size_t)N_NODES * D * 2);
    unsigned short* h_o   = (unsigned short*)alloc((size_t)N_NODES * D * 2);
    unsigned short* h_e   = (unsigned short*)alloc((size_t)N_NODES * D * 2);
    unsigned short* obf0  = (unsigned short*)alloc((size_t)N_NODES * D * 2);
    unsigned short* obf1  = (unsigned short*)alloc((size_t)N_NODES * D * 2);
    unsigned short* wt_po = (unsigned short*)alloc((size_t)D * D * 2);
    unsigned short* wt_pe = (unsigned short*)alloc((size_t)D * D * 2);
    unsigned short* wt_kl = (unsigned short*)alloc((size_t)D * D * 2);
    float* aS0 = (float*)alloc((size_t)N_NODES * H * 4);
    float* aD0 = (float*)alloc((size_t)N_NODES * H * 4);
    float* aS1 = (float*)alloc((size_t)N_NODES * H * 4);
    float* aD1 = (float*)alloc((size_t)N_NODES * H * 4);
    // contiguous zeroed region: colsum[1024] | ksum[1024] | deg[2N]
    int* misc    = (int*)alloc((2048 + 2 * N_NODES) * 4);
    float* colsum = (float*)misc;
    float* ksum   = colsum + 1024;
    int* deg      = misc + 2048;
    int* cursor  = (int*)alloc(2 * N_NODES * 4);
    int* rowptr  = (int*)alloc((2 * N_NODES + 1) * 4);
    int* partials= (int*)alloc(256 * 4);
    int* csr     = (int*)alloc(2 * N_EDGES * 4);

    const int NSC = 2 * N_NODES;
    const int NB1 = (NSC + 1023) / 1024;              // 196
    const int EH  = (2 * N_EDGES + 255) / 256;        // 1172

    hipMemsetAsync(misc, 0, (size_t)(2048 + 2 * N_NODES) * 4, stream);

    // CSR build
    hist_edges<<<EH, 256, 0, stream>>>(e2o, o2o, deg);
    scan1<<<NB1, 256, 0, stream>>>(deg, rowptr, partials, NSC);
    scan23<<<NB1, 256, 0, stream>>>(rowptr, partials, cursor, NSC, 2 * N_EDGES, NB1);
    fill_csr<<<EH, 256, 0, stream>>>(e2o, o2o, cursor, csr);

    // weights -> bf16 W^T (one dispatch), inputs -> bf16 (one dispatch)
    transpose3<<<dim3(16, 16, 3), 256, 0, stream>>>(pow_, pew, klw, wt_po, wt_pe, wt_kl);
    convert2<<<(2 * N_NODES * D / 4) / 256, 256, 0, stream>>>(
        (const float4*)x_o, (const float4*)x_e, (uint2*)xbf_o, (uint2*)xbf_e);

    // merged projections + fused attention dots
    gemm_proj2<<<2 * NBLKG, 256, 0, stream>>>(
        xbf_o, xbf_e, wt_po, wt_pe, pob, peb, h_o, h_e,
        ad_e2o, as_o2o, ad_o2o, aD0, aS1, aD1,
        as_e2o, aS0);

    // merged aggregation, column sums, semantic-K GEMMs
    aggregate2<<<(2 * N_NODES * 64) / 256, 256, 0, stream>>>(
        rowptr, csr, aS0, aD0, h_e, aS1, aD1, h_o, obf0, obf1);
    colsum2<<<2 * NBR, 256, 0, stream>>>(obf0, obf1, colsum);
    gemm_tanh2<<<2 * NBLKG, 256, 0, stream>>>(obf0, obf1, wt_kl, klb, ksum);

    finalize<<<1, 256, 0, stream>>>(ksum, colsum, qsem, linw, linb, (float*)d_out);
}